// Round 8
// baseline (101.868 us; speedup 1.0000x reference)
//
#include <hip/hip_runtime.h>

// LowBitMixIn: out[b,o,t] = sum_{d=1..7} mixer[o,(o-d)&1023] * x[b, perm[(o-d)&1023], t]
// B=16, F=1024, T=4096, float32. Memory-bound streaming.
//
// R8: extend the confirmed granularity lever (R7: 1KB->2KB = -7%) to 4KB
// contiguous per wave row access (4x dwordx4 per lane). OCH 32->16,
// ROWS_PER_BLOCK 128->64 to keep 1024 blocks. VGPR ~155 -> bounds (256,3).

#define F_DIM 1024
#define T_DIM 4096
#define T4 (T_DIM / 4)   // 1024 float4 per row
#define OCH 16           // o-rows per wave
#define ROWS_PER_BLOCK 64
#define NH 4             // float4s per lane per row (4KB per wave access)

typedef float fvec4 __attribute__((ext_vector_type(4)));

__global__ __launch_bounds__(256, 3) void lowbit_mix_kernel(
    const float* __restrict__ x, const float* __restrict__ mixer,
    const int* __restrict__ perm, float* __restrict__ out)
{
    __shared__ float sCoef[ROWS_PER_BLOCK][8]; // [row_in_block][d-1], d=1..8 (slot 8 unused zero)
    __shared__ int   sPerm[ROWS_PER_BLOCK + 8];

    const int tid  = threadIdx.x;
    const int lane = tid & 63;
    const int w    = tid >> 6;                        // wave 0..3
    const int t4   = blockIdx.x * (64 * NH) + lane;   // covers t4 + {0,64,128,192}
    const int block_o0 = blockIdx.y * ROWS_PER_BLOCK;
    const int b    = blockIdx.z;

    // ---- stage coefs + perm into LDS (once per block) ----
#pragma unroll
    for (int idx = tid; idx < ROWS_PER_BLOCK * 8; idx += 256) {
        const int r = idx >> 3;
        const int d = (idx & 7) + 1;
        const int o = block_o0 + r;
        sCoef[r][d - 1] = mixer[(size_t)o * F_DIM + ((o - d) & (F_DIM - 1))];
    }
    if (tid < ROWS_PER_BLOCK + 8) {
        sPerm[tid] = perm[(block_o0 - 8 + tid) & (F_DIM - 1)];
    }
    __syncthreads();

    const fvec4* __restrict__ xb =
        reinterpret_cast<const fvec4*>(x) + (size_t)b * F_DIM * T4;
    fvec4* __restrict__ ob =
        reinterpret_cast<fvec4*>(out) + (size_t)b * F_DIM * T4;

    const int wbase = w * OCH;                        // wave's first row within block
    // Rolling window: win[k][h] = x[row i=o-7+k][t4 + 64h]
    fvec4 win[7][NH];
#pragma unroll
    for (int k = 0; k < 7; ++k) {
        const size_t rowoff = (size_t)sPerm[wbase + 1 + k] * T4 + t4;
#pragma unroll
        for (int h = 0; h < NH; ++h) win[k][h] = xb[rowoff + 64 * h];
    }

#pragma unroll
    for (int oi = 0; oi < OCH; ++oi) {
        const int r = wbase + oi;                     // row within block
        const int o = block_o0 + r;                   // global output row

        // prefetch next row (4KB contiguous), consumed at END of this iter's chain
        fvec4 nxt[NH];
        if (oi != OCH - 1) {
            const size_t rowoff = (size_t)sPerm[r + 8] * T4 + t4;
#pragma unroll
            for (int h = 0; h < NH; ++h) nxt[h] = xb[rowoff + 64 * h];
        }

        fvec4 acc[NH];
#pragma unroll
        for (int h = 0; h < NH; ++h) acc[h] = (fvec4)(0.f);
        // oldest (d=7) first ... newest (d=1) last
#pragma unroll
        for (int d = 7; d >= 1; --d) {
            const float c = sCoef[r][d - 1];
#pragma unroll
            for (int h = 0; h < NH; ++h) acc[h] += c * win[7 - d][h];
        }
        const size_t ooff = (size_t)o * T4 + t4;
#pragma unroll
        for (int h = 0; h < NH; ++h)
            __builtin_nontemporal_store(acc[h], &ob[ooff + 64 * h]);

        if (oi != OCH - 1) {
#pragma unroll
            for (int k = 0; k < 6; ++k)
#pragma unroll
                for (int h = 0; h < NH; ++h) win[k][h] = win[k + 1][h];
#pragma unroll
            for (int h = 0; h < NH; ++h) win[6][h] = nxt[h];
        }
    }
}

extern "C" void kernel_launch(void* const* d_in, const int* in_sizes, int n_in,
                              void* d_out, int out_size, void* d_ws, size_t ws_size,
                              hipStream_t stream) {
    const float* x     = (const float*)d_in[0];   // (16, 1024, 4096) f32
    const float* mixer = (const float*)d_in[1];   // (1024, 1024) f32
    const int*   perm  = (const int*)d_in[2];     // (1024,) i32
    float*       out   = (float*)d_out;           // (16, 1024, 4096) f32

    dim3 grid(T_DIM / (256 * NH) * 256 / 256,      // = T4/(64*NH) = 4 t-chunks (4KB each)
              F_DIM / ROWS_PER_BLOCK,              // 16 o-tiles (64 rows: 4 waves x 16)
              16);                                 // batch
    dim3 block(256);
    lowbit_mix_kernel<<<grid, block, 0, stream>>>(x, mixer, perm, out);
}

// Round 9
// 90.560 us; speedup vs baseline: 1.1249x; 1.1249x over previous
//
#include <hip/hip_runtime.h>

// LowBitMixIn: out[b,o,t] = sum_{d=1..7} mixer[o,(o-d)&1023] * x[b, perm[(o-d)&1023], t]
// B=16, F=1024, T=4096, float32. Memory-bound streaming.
//
// R9: R7's per-wave structure (2KB contiguous per row access, rolling 7-row
// window, LDS coefs, nt stores) with the wave->work mapping swapped: the 4
// waves of a block share the SAME 32 output rows and cover 4 ADJACENT 2KB
// t-chunks. Near-lockstep waves => ~8KB effective granules at the memory
// controller, with R7's occupancy/VGPR/amplification untouched.

#define F_DIM 1024
#define T_DIM 4096
#define T4 (T_DIM / 4)   // 1024 float4 per row
#define OCH 32           // o-rows per block (shared by all 4 waves)

typedef float fvec4 __attribute__((ext_vector_type(4)));

__global__ __launch_bounds__(256, 4) void lowbit_mix_kernel(
    const float* __restrict__ x, const float* __restrict__ mixer,
    const int* __restrict__ perm, float* __restrict__ out)
{
    __shared__ float sCoef[OCH][8];   // [row][d-1], d=1..8 (slot 8 unused zero)
    __shared__ int   sPerm[OCH + 8];  // perm[(block_o0 - 8 + j) & 1023]

    const int tid  = threadIdx.x;
    const int lane = tid & 63;
    const int w    = tid >> 6;                        // wave 0..3
    // block covers 512 t4 (8KB); wave w owns the 2KB stripe [w*128, w*128+128)
    const int t4   = blockIdx.x * 512 + w * 128 + lane;
    const int block_o0 = blockIdx.y * OCH;
    const int b    = blockIdx.z;

    // ---- stage coefs + perm into LDS (once per block) ----
    {
        const int r = tid >> 3;                       // 0..31
        const int d = (tid & 7) + 1;                  // 1..8
        const int o = block_o0 + r;
        sCoef[r][d - 1] = mixer[(size_t)o * F_DIM + ((o - d) & (F_DIM - 1))];
        if (tid < OCH + 8) {
            sPerm[tid] = perm[(block_o0 - 8 + tid) & (F_DIM - 1)];
        }
    }
    __syncthreads();

    const fvec4* __restrict__ xb =
        reinterpret_cast<const fvec4*>(x) + (size_t)b * F_DIM * T4;
    fvec4* __restrict__ ob =
        reinterpret_cast<fvec4*>(out) + (size_t)b * F_DIM * T4;

    // Rolling window: win[k][h] = x[row i=o-7+k][t4 + 64h]
    fvec4 win[7][2];
#pragma unroll
    for (int k = 0; k < 7; ++k) {
        const size_t rowoff = (size_t)sPerm[1 + k] * T4 + t4;
        win[k][0] = xb[rowoff];
        win[k][1] = xb[rowoff + 64];
    }

#pragma unroll
    for (int oi = 0; oi < OCH; ++oi) {
        const int o = block_o0 + oi;                  // global output row

        // prefetch next row (2KB/wave, 8KB/block), consumed end of next iter
        fvec4 nxt0, nxt1;
        if (oi != OCH - 1) {
            const size_t rowoff = (size_t)sPerm[oi + 8] * T4 + t4;
            nxt0 = xb[rowoff];
            nxt1 = xb[rowoff + 64];
        }

        fvec4 acc0 = (fvec4)(0.f);
        fvec4 acc1 = (fvec4)(0.f);
        // oldest (d=7) first ... newest (d=1) last
#pragma unroll
        for (int d = 7; d >= 1; --d) {
            const float c = sCoef[oi][d - 1];
            acc0 += c * win[7 - d][0];
            acc1 += c * win[7 - d][1];
        }
        const size_t ooff = (size_t)o * T4 + t4;
        __builtin_nontemporal_store(acc0, &ob[ooff]);
        __builtin_nontemporal_store(acc1, &ob[ooff + 64]);

        if (oi != OCH - 1) {
#pragma unroll
            for (int k = 0; k < 6; ++k) { win[k][0] = win[k + 1][0]; win[k][1] = win[k + 1][1]; }
            win[6][0] = nxt0;
            win[6][1] = nxt1;
        }
    }
}

extern "C" void kernel_launch(void* const* d_in, const int* in_sizes, int n_in,
                              void* d_out, int out_size, void* d_ws, size_t ws_size,
                              hipStream_t stream) {
    const float* x     = (const float*)d_in[0];   // (16, 1024, 4096) f32
    const float* mixer = (const float*)d_in[1];   // (1024, 1024) f32
    const int*   perm  = (const int*)d_in[2];     // (1024,) i32
    float*       out   = (float*)d_out;           // (16, 1024, 4096) f32

    dim3 grid(T4 / 512,        // 2 t-chunks (block covers 512 t4 = 8KB)
              F_DIM / OCH,     // 32 o-tiles (32 rows, shared by 4 waves)
              16);             // batch  => 2*32*16 = 1024 blocks
    dim3 block(256);
    lowbit_mix_kernel<<<grid, block, 0, stream>>>(x, mixer, perm, out);
}

// Round 10
// 89.376 us; speedup vs baseline: 1.1398x; 1.0133x over previous
//
#include <hip/hip_runtime.h>

// LowBitMixIn: out[b,o,t] = sum_{d=1..7} mixer[o,(o-d)&1023] * x[b, perm[(o-d)&1023], t]
// B=16, F=1024, T=4096, float32. Memory-bound streaming.
//
// R10: R9 (cross-wave-adjacent 2KB/wave rows, LDS coefs, nt stores) + REAL
// 4-deep prefetch. R5's depth test was defeated by the compiler (VGPR=32
// proved the pend queue was sunk to use points). Here every prefetch batch is
// followed by __builtin_amdgcn_sched_barrier(0) so loads issue where written;
// all pend indices are compile-time (full unroll). Expect VGPR ~90-110.

#define F_DIM 1024
#define T_DIM 4096
#define T4 (T_DIM / 4)   // 1024 float4 per row
#define OCH 32           // o-rows per block (shared by all 4 waves)
#define PF 4             // prefetch distance (rows in flight)

typedef float fvec4 __attribute__((ext_vector_type(4)));

__global__ __launch_bounds__(256, 4) void lowbit_mix_kernel(
    const float* __restrict__ x, const float* __restrict__ mixer,
    const int* __restrict__ perm, float* __restrict__ out)
{
    __shared__ float sCoef[OCH][8];   // [row][d-1], d=1..8 (slot 8 unused zero)
    __shared__ int   sPerm[OCH + 8];  // perm[(block_o0 - 8 + j) & 1023]

    const int tid  = threadIdx.x;
    const int lane = tid & 63;
    const int w    = tid >> 6;                        // wave 0..3
    // block covers 512 t4 (8KB); wave w owns the 2KB stripe [w*128, w*128+128)
    const int t4   = blockIdx.x * 512 + w * 128 + lane;
    const int block_o0 = blockIdx.y * OCH;
    const int b    = blockIdx.z;

    // ---- stage coefs + perm into LDS (once per block) ----
    {
        const int r = tid >> 3;                       // 0..31
        const int d = (tid & 7) + 1;                  // 1..8
        const int o = block_o0 + r;
        sCoef[r][d - 1] = mixer[(size_t)o * F_DIM + ((o - d) & (F_DIM - 1))];
        if (tid < OCH + 8) {
            sPerm[tid] = perm[(block_o0 - 8 + tid) & (F_DIM - 1)];
        }
    }
    __syncthreads();

    const fvec4* __restrict__ xb =
        reinterpret_cast<const fvec4*>(x) + (size_t)b * F_DIM * T4;
    fvec4* __restrict__ ob =
        reinterpret_cast<fvec4*>(out) + (size_t)b * F_DIM * T4;

    // Rolling window: win[k][h] = x[input row o-7+k][t4 + 64h]
    fvec4 win[7][2];
#pragma unroll
    for (int k = 0; k < 7; ++k) {
        const size_t rowoff = (size_t)sPerm[1 + k] * T4 + t4;
        win[k][0] = xb[rowoff];
        win[k][1] = xb[rowoff + 64];
    }
    // Prefetch queue: pend[j] holds input row o0+j (consumed at iter j's end)
    fvec4 pend[PF][2];
#pragma unroll
    for (int j = 0; j < PF; ++j) {
        const size_t rowoff = (size_t)sPerm[8 + j] * T4 + t4;
        pend[j][0] = xb[rowoff];
        pend[j][1] = xb[rowoff + 64];
    }
    __builtin_amdgcn_sched_barrier(0);   // pin: prefetches issue here, not at use

#pragma unroll
    for (int oi = 0; oi < OCH; ++oi) {
        const int o = block_o0 + oi;                  // global output row

        fvec4 acc0 = (fvec4)(0.f);
        fvec4 acc1 = (fvec4)(0.f);
        // oldest (d=7) first ... newest (d=1) last
#pragma unroll
        for (int d = 7; d >= 1; --d) {
            const float c = sCoef[oi][d - 1];
            acc0 += c * win[7 - d][0];
            acc1 += c * win[7 - d][1];
        }
        const size_t ooff = (size_t)o * T4 + t4;
        __builtin_nontemporal_store(acc0, &ob[ooff]);
        __builtin_nontemporal_store(acc1, &ob[ooff + 64]);

        if (oi != OCH - 1) {
            // shift window; consume pend slot holding input row o0+oi
#pragma unroll
            for (int k = 0; k < 6; ++k) { win[k][0] = win[k + 1][0]; win[k][1] = win[k + 1][1]; }
            win[6][0] = pend[oi & (PF - 1)][0];
            win[6][1] = pend[oi & (PF - 1)][1];
            // refill slot with input row o0+oi+PF (needed at iter oi+PF; last input o0+30)
            if (oi + PF <= OCH - 2) {
                const size_t rowoff = (size_t)sPerm[8 + oi + PF] * T4 + t4;
                pend[oi & (PF - 1)][0] = xb[rowoff];
                pend[oi & (PF - 1)][1] = xb[rowoff + 64];
                __builtin_amdgcn_sched_barrier(0);  // pin issue point
            }
        }
    }
}

extern "C" void kernel_launch(void* const* d_in, const int* in_sizes, int n_in,
                              void* d_out, int out_size, void* d_ws, size_t ws_size,
                              hipStream_t stream) {
    const float* x     = (const float*)d_in[0];   // (16, 1024, 4096) f32
    const float* mixer = (const float*)d_in[1];   // (1024, 1024) f32
    const int*   perm  = (const int*)d_in[2];     // (1024,) i32
    float*       out   = (float*)d_out;           // (16, 1024, 4096) f32

    dim3 grid(T4 / 512,        // 2 t-chunks (block covers 512 t4 = 8KB)
              F_DIM / OCH,     // 32 o-tiles (32 rows, shared by 4 waves)
              16);             // batch  => 1024 blocks
    dim3 block(256);
    lowbit_mix_kernel<<<grid, block, 0, stream>>>(x, mixer, perm, out);
}